// Round 1
// baseline (519.926 us; speedup 1.0000x reference)
//
#include <hip/hip_runtime.h>
#include <math.h>

#define N_NODES 50000
#define N_EDGES 800000
// NODE_IN=128, EDGE_IN=64, EFT=32, OUT=64

__device__ __forceinline__ unsigned flip_f(float f) {
    unsigned u = __float_as_uint(f);
    return (u & 0x80000000u) ? ~u : (u | 0x80000000u);
}
__device__ __forceinline__ float unflip_f(unsigned v) {
    unsigned u = (v & 0x80000000u) ? (v & 0x7fffffffu) : ~v;
    return __uint_as_float(u);
}

// Derived weights: Wc[i][m] = sum_k W2[i][64+k]*We[k][m]; wca[m] = sum_k Wa[64+k]*We[k][m]
__global__ void kw_kernel(const float* __restrict__ W2, const float* __restrict__ We,
                          const float* __restrict__ Wa,
                          float* __restrict__ Wc, float* __restrict__ wca) {
    int t = blockIdx.x * blockDim.x + threadIdx.x;
    if (t < 64 * 64) {
        int i = t >> 6, m = t & 63;
        float acc = 0.f;
        #pragma unroll
        for (int k = 0; k < 32; ++k) acc += W2[i * 96 + 64 + k] * We[k * 64 + m];
        Wc[t] = acc;
    }
    if (t < 64) {
        float acc = 0.f;
        #pragma unroll
        for (int k = 0; k < 32; ++k) acc += Wa[64 + k] * We[k * 64 + t];
        wca[t] = acc;
    }
}

// Per-node: z = h@Wn^T, y = z@W2a^T, asrc = z.Wa[0:64], adst = z.Wa[96:160]
__global__ __launch_bounds__(256) void node_kernel(
    const float* __restrict__ h, const float* __restrict__ Wn,
    const float* __restrict__ W2, const float* __restrict__ Wa,
    float* __restrict__ z, float* __restrict__ y,
    float* __restrict__ asrc, float* __restrict__ adst)
{
    __shared__ float sWn[64 * 129];   // padded: bank-conflict-free
    __shared__ float sW2a[64 * 65];
    __shared__ float sWa0[64], sWa2[64];
    __shared__ float sh[4][128];
    __shared__ float sz[4][64];

    int t = threadIdx.x;
    for (int idx = t; idx < 64 * 128; idx += 256) {
        int r = idx >> 7, c = idx & 127;
        sWn[r * 129 + c] = Wn[idx];
    }
    for (int idx = t; idx < 64 * 64; idx += 256) {
        int r = idx >> 6, c = idx & 63;
        sW2a[r * 65 + c] = W2[r * 96 + c];
    }
    if (t < 64) { sWa0[t] = Wa[t]; sWa2[t] = Wa[96 + t]; }
    __syncthreads();

    int w = t >> 6, l = t & 63;
    for (int n0 = blockIdx.x * 4; n0 < N_NODES; n0 += gridDim.x * 4) {
        for (int idx = t; idx < 4 * 128; idx += 256) {
            int nn = idx >> 7, c = idx & 127;
            if (n0 + nn < N_NODES) sh[nn][c] = h[(size_t)(n0 + nn) * 128 + c];
        }
        __syncthreads();
        int n = n0 + w;
        float zl = 0.f;
        if (n < N_NODES) {
            #pragma unroll 8
            for (int k = 0; k < 128; ++k) zl += sh[w][k] * sWn[l * 129 + k];
            sz[w][l] = zl;
            z[(size_t)n * 64 + l] = zl;
        }
        __syncthreads();
        if (n < N_NODES) {
            float yl = 0.f;
            #pragma unroll 8
            for (int k = 0; k < 64; ++k) yl += sz[w][k] * sW2a[l * 65 + k];
            y[(size_t)n * 64 + l] = yl;
            float p0 = zl * sWa0[l];
            float p1 = zl * sWa2[l];
            #pragma unroll
            for (int off = 32; off > 0; off >>= 1) {
                p0 += __shfl_xor(p0, off);
                p1 += __shfl_xor(p1, off);
            }
            if (l == 0) { asrc[n] = p0; adst[n] = p1; }
        }
        __syncthreads();
    }
}

// Per-edge logit: s = leaky_relu(asrc[src] + ef.wca + adst[dst]); segmax via flipped-uint atomicMax
__global__ __launch_bounds__(256) void edge_logit_kernel(
    const float* __restrict__ edge_feat, const int* __restrict__ src,
    const int* __restrict__ dst, const float* __restrict__ asrc,
    const float* __restrict__ adst, const float* __restrict__ wca,
    float* __restrict__ sx, unsigned* __restrict__ segmax)
{
    int t = blockIdx.x * 256 + threadIdx.x;
    int e = t >> 4;  // 16 lanes per edge, float4 each
    int l = t & 15;
    if (e >= N_EDGES) return;
    const float4 v = reinterpret_cast<const float4*>(edge_feat)[(size_t)e * 16 + l];
    const float4 w = reinterpret_cast<const float4*>(wca)[l];
    float p = v.x * w.x + v.y * w.y + v.z * w.z + v.w * w.w;
    p += __shfl_xor(p, 8);
    p += __shfl_xor(p, 4);
    p += __shfl_xor(p, 2);
    p += __shfl_xor(p, 1);
    if (l == 0) {
        int d = dst[e];
        float a = asrc[src[e]] + p + adst[d];
        float s = a > 0.f ? a : 0.01f * a;
        sx[e] = s;
        atomicMax(&segmax[d], flip_f(s));
    }
}

// ex = exp(s - segmax[dst]); denom[dst] += ex (sx overwritten in place with ex)
__global__ __launch_bounds__(256) void edge_exp_kernel(
    const int* __restrict__ dst, const unsigned* __restrict__ segmax,
    float* __restrict__ sx, float* __restrict__ denom)
{
    int e = blockIdx.x * 256 + threadIdx.x;
    if (e >= N_EDGES) return;
    int d = dst[e];
    float m = unflip_f(segmax[d]);
    float ex = expf(sx[e] - m);
    sx[e] = ex;
    atomicAdd(&denom[d], ex);
}

// out[dst] += (ex/denom[dst]) * (y[src] + edge_feat[e]@Wc^T)
__global__ __launch_bounds__(256) void edge_agg_kernel(
    const float* __restrict__ edge_feat, const int* __restrict__ src,
    const int* __restrict__ dst, const float* __restrict__ y,
    const float* __restrict__ sx, const float* __restrict__ denom,
    const float* __restrict__ Wc, float* __restrict__ out)
{
    __shared__ float sWc[64 * 65];
    __shared__ float sef[4][64];
    int t = threadIdx.x;
    for (int idx = t; idx < 64 * 64; idx += 256) {
        sWc[(idx >> 6) * 65 + (idx & 63)] = Wc[idx];
    }
    __syncthreads();
    int w = t >> 6, l = t & 63;
    for (int e0 = blockIdx.x * 4; e0 < N_EDGES; e0 += gridDim.x * 4) {
        int e = e0 + w;
        bool act = e < N_EDGES;
        float efl = 0.f;
        if (act) efl = edge_feat[(size_t)e * 64 + l];
        sef[w][l] = efl;
        __syncthreads();
        if (act) {
            float g = 0.f;
            #pragma unroll 8
            for (int m = 0; m < 64; ++m) g += sef[w][m] * sWc[l * 65 + m];
            int d = dst[e], sN = src[e];
            float alpha = sx[e] / denom[d];
            float val = alpha * (y[(size_t)sN * 64 + l] + g);
            atomicAdd(&out[(size_t)d * 64 + l], val);
        }
        __syncthreads();
    }
}

// deg==0 nodes keep z
__global__ void fixup_kernel(const float* __restrict__ denom,
                             const float* __restrict__ z, float* __restrict__ out)
{
    int t = blockIdx.x * 256 + threadIdx.x;
    if (t >= N_NODES * 64) return;
    int n = t >> 6;
    if (denom[n] == 0.f) out[t] = z[t];
}

extern "C" void kernel_launch(void* const* d_in, const int* in_sizes, int n_in,
                              void* d_out, int out_size, void* d_ws, size_t ws_size,
                              hipStream_t stream) {
    const float* h         = (const float*)d_in[0];
    const float* edge_feat = (const float*)d_in[1];
    const int*   src       = (const int*)d_in[2];
    const int*   dst       = (const int*)d_in[3];
    const float* Wn        = (const float*)d_in[4];
    const float* We        = (const float*)d_in[5];
    const float* Wa        = (const float*)d_in[6];
    const float* W2        = (const float*)d_in[7];
    float* out = (float*)d_out;

    char* p = (char*)d_ws;
    float*    z      = (float*)p;    p += (size_t)N_NODES * 64 * 4;
    float*    y      = (float*)p;    p += (size_t)N_NODES * 64 * 4;
    float*    asrc   = (float*)p;    p += (size_t)N_NODES * 4;
    float*    adst   = (float*)p;    p += (size_t)N_NODES * 4;
    unsigned* segmax = (unsigned*)p; p += (size_t)N_NODES * 4;
    float*    denom  = (float*)p;    p += (size_t)N_NODES * 4;
    float*    sx     = (float*)p;    p += (size_t)N_EDGES * 4;
    float*    Wc     = (float*)p;    p += (size_t)64 * 64 * 4;
    float*    wca    = (float*)p;    p += (size_t)64 * 4;

    hipMemsetAsync(out, 0, (size_t)N_NODES * 64 * 4, stream);
    hipMemsetAsync(segmax, 0, (size_t)N_NODES * 4, stream);
    hipMemsetAsync(denom, 0, (size_t)N_NODES * 4, stream);

    kw_kernel<<<16, 256, 0, stream>>>(W2, We, Wa, Wc, wca);
    node_kernel<<<1024, 256, 0, stream>>>(h, Wn, W2, Wa, z, y, asrc, adst);
    edge_logit_kernel<<<(N_EDGES * 16 + 255) / 256, 256, 0, stream>>>(
        edge_feat, src, dst, asrc, adst, wca, sx, segmax);
    edge_exp_kernel<<<(N_EDGES + 255) / 256, 256, 0, stream>>>(dst, segmax, sx, denom);
    edge_agg_kernel<<<4096, 256, 0, stream>>>(edge_feat, src, dst, y, sx, denom, Wc, out);
    fixup_kernel<<<(N_NODES * 64 + 255) / 256, 256, 0, stream>>>(denom, z, out);
}

// Round 2
// 395.165 us; speedup vs baseline: 1.3157x; 1.3157x over previous
//
#include <hip/hip_runtime.h>
#include <math.h>

#define N_NODES 50000
#define N_EDGES 800000
#define NB1 196  // ceil(50000/256)

// Derived weights:
//   Wcat[i][m]    = Wc[i][m]  = sum_k W2[i][64+k]*We[k][m]   (edge-feat path, m<64)
//   Wcat[i][64+m] = W2a[i][m] = W2[i*96+m]                   (z-src path)
//   wca[m] = sum_k Wa[64+k]*We[k][m]
__global__ void kw_kernel(const float* __restrict__ W2, const float* __restrict__ We,
                          const float* __restrict__ Wa,
                          float* __restrict__ Wcat, float* __restrict__ wca) {
    int t = blockIdx.x * blockDim.x + threadIdx.x;
    if (t < 64 * 64) {
        int i = t >> 6, m = t & 63;
        float acc = 0.f;
        #pragma unroll
        for (int k = 0; k < 32; ++k) acc += W2[i * 96 + 64 + k] * We[k * 64 + m];
        Wcat[i * 128 + m] = acc;
        Wcat[i * 128 + 64 + m] = W2[i * 96 + m];
    }
    if (t < 64) {
        float acc = 0.f;
        #pragma unroll
        for (int k = 0; k < 32; ++k) acc += Wa[64 + k] * We[k * 64 + t];
        wca[t] = acc;
    }
}

// Per-node: z = h@Wn^T, asrc = z.Wa[0:64], adst = z.Wa[96:160]   (y eliminated)
__global__ __launch_bounds__(256) void node_kernel(
    const float* __restrict__ h, const float* __restrict__ Wn,
    const float* __restrict__ Wa,
    float* __restrict__ z, float* __restrict__ asrc, float* __restrict__ adst)
{
    __shared__ float sWn[64 * 132];   // stride 132: 16B-aligned rows, conflict-free b128
    __shared__ float sh[4][128];
    int t = threadIdx.x;
    for (int idx = t; idx < 64 * 128; idx += 256) {
        int r = idx >> 7, c = idx & 127;
        sWn[r * 132 + c] = Wn[idx];
    }
    int w = t >> 6, l = t & 63;
    float wa0 = Wa[l], wa2 = Wa[96 + l];
    __syncthreads();
    for (int n0 = blockIdx.x * 4; n0 < N_NODES; n0 += gridDim.x * 4) {
        if (t < 128) {
            int nn = t >> 5, c4 = t & 31;
            int n = n0 + nn;
            if (n < N_NODES)
                ((float4*)&sh[nn][0])[c4] = ((const float4*)h)[(size_t)n * 32 + c4];
        }
        __syncthreads();
        int n = n0 + w;
        if (n < N_NODES) {
            float acc = 0.f;
            #pragma unroll
            for (int q = 0; q < 32; ++q) {
                float4 wv = *(const float4*)&sWn[l * 132 + q * 4];
                float4 hv = *(const float4*)&sh[w][q * 4];
                acc += wv.x * hv.x + wv.y * hv.y + wv.z * hv.z + wv.w * hv.w;
            }
            z[(size_t)n * 64 + l] = acc;
            float p0 = acc * wa0, p1 = acc * wa2;
            #pragma unroll
            for (int off = 32; off; off >>= 1) {
                p0 += __shfl_xor(p0, off);
                p1 += __shfl_xor(p1, off);
            }
            if (l == 0) { asrc[n] = p0; adst[n] = p1; }
        }
        __syncthreads();
    }
}

// ---- CSR build ----
__global__ void hist_kernel(const int* __restrict__ dst, int* __restrict__ degi) {
    int e = blockIdx.x * 256 + threadIdx.x;
    if (e < N_EDGES) atomicAdd(&degi[dst[e]], 1);
}

__global__ __launch_bounds__(256) void scan1_kernel(const int* __restrict__ degi,
                                                    int* __restrict__ partial) {
    int t = threadIdx.x, i = blockIdx.x * 256 + t;
    int d = (i < N_NODES) ? degi[i] : 0;
    #pragma unroll
    for (int off = 32; off; off >>= 1) d += __shfl_down(d, off);
    __shared__ int wsum[4];
    if ((t & 63) == 0) wsum[t >> 6] = d;
    __syncthreads();
    if (t == 0) partial[blockIdx.x] = wsum[0] + wsum[1] + wsum[2] + wsum[3];
}

__global__ __launch_bounds__(256) void scan2_kernel(int* __restrict__ partial) {
    __shared__ int s[256];
    int t = threadIdx.x;
    int v = (t < NB1) ? partial[t] : 0;
    s[t] = v; __syncthreads();
    for (int off = 1; off < 256; off <<= 1) {
        int x = (t >= off) ? s[t - off] : 0;
        __syncthreads();
        s[t] += x;
        __syncthreads();
    }
    if (t < NB1) partial[t] = s[t] - v;   // exclusive, in place
}

__global__ __launch_bounds__(256) void scan3_kernel(const int* __restrict__ degi,
                                                    const int* __restrict__ partial,
                                                    int* __restrict__ start,
                                                    int* __restrict__ cursor) {
    __shared__ int s[256];
    int t = threadIdx.x, i = blockIdx.x * 256 + t;
    int d = (i < N_NODES) ? degi[i] : 0;
    s[t] = d; __syncthreads();
    for (int off = 1; off < 256; off <<= 1) {
        int x = (t >= off) ? s[t - off] : 0;
        __syncthreads();
        s[t] += x;
        __syncthreads();
    }
    if (i < N_NODES) {
        int st = partial[blockIdx.x] + s[t] - d;
        start[i] = st;
        cursor[i] = st;
    }
}

__global__ void scatter_kernel(const int* __restrict__ src, const int* __restrict__ dst,
                               int* __restrict__ cursor, int2* __restrict__ edata) {
    int e = blockIdx.x * 256 + threadIdx.x;
    if (e < N_EDGES) {
        int d = dst[e];
        int pos = atomicAdd(&cursor[d], 1);
        edata[pos] = make_int2(e, src[e]);
    }
}

// ---- aggregation: one wave per node, edge_feat read once, no fp atomics ----
__global__ __launch_bounds__(256) void agg_kernel(
    const float* __restrict__ edge_feat, const int2* __restrict__ edata,
    const int* __restrict__ start, const int* __restrict__ degi,
    const float* __restrict__ asrc, const float* __restrict__ adst,
    const float* __restrict__ z, const float* __restrict__ wca,
    const float* __restrict__ Wcat, float* __restrict__ out)
{
    __shared__ float stu[4][132];
    int t = threadIdx.x, w = t >> 6, l = t & 63;
    float wcal = wca[l];
    int d = blockIdx.x * 4 + w;          // grid exact: 12500*4 = 50000
    int base = start[d], deg = degi[d];
    float ad = adst[d];
    float tm = 0.f, um = 0.f, den = 0.f;
    for (int i = 0; i < deg; ++i) {
        int2 es = edata[base + i];
        int e  = __builtin_amdgcn_readfirstlane(es.x);
        int sN = __builtin_amdgcn_readfirstlane(es.y);
        float efl = edge_feat[(size_t)e * 64 + l];
        float zl  = z[(size_t)sN * 64 + l];
        float p = efl * wcal;
        #pragma unroll
        for (int off = 32; off; off >>= 1) p += __shfl_xor(p, off);
        float a = asrc[sN] + p + ad;
        float s = a > 0.f ? a : 0.01f * a;
        float ex = __expf(s);     // segmax shift is mathematically redundant; |s| ~ O(3)
        tm += ex * efl;
        um += ex * zl;
        den += ex;
    }
    // per-node epilogue: out = ([t,u] @ Wcat^T) / den   (wave-local LDS exchange)
    stu[w][l] = tm;
    stu[w][64 + l] = um;
    if (deg > 0) {
        float acc = 0.f;
        #pragma unroll
        for (int q = 0; q < 32; ++q) {
            float4 wv = *(const float4*)&Wcat[l * 128 + q * 4];
            float4 tv = *(const float4*)&stu[w][q * 4];
            acc += wv.x * tv.x + wv.y * tv.y + wv.z * tv.z + wv.w * tv.w;
        }
        out[(size_t)d * 64 + l] = acc / den;
    } else {
        out[(size_t)d * 64 + l] = z[(size_t)d * 64 + l];
    }
}

extern "C" void kernel_launch(void* const* d_in, const int* in_sizes, int n_in,
                              void* d_out, int out_size, void* d_ws, size_t ws_size,
                              hipStream_t stream) {
    const float* h         = (const float*)d_in[0];
    const float* edge_feat = (const float*)d_in[1];
    const int*   src       = (const int*)d_in[2];
    const int*   dst       = (const int*)d_in[3];
    const float* Wn        = (const float*)d_in[4];
    const float* We        = (const float*)d_in[5];
    const float* Wa        = (const float*)d_in[6];
    const float* W2        = (const float*)d_in[7];
    float* out = (float*)d_out;

    char* p = (char*)d_ws;
    float* z      = (float*)p; p += (size_t)N_NODES * 64 * 4;
    float* asrc   = (float*)p; p += (size_t)N_NODES * 4;
    float* adst   = (float*)p; p += (size_t)N_NODES * 4;
    int*   degi   = (int*)p;   p += (size_t)N_NODES * 4;
    int*   start  = (int*)p;   p += (size_t)N_NODES * 4;
    int*   cursor = (int*)p;   p += (size_t)N_NODES * 4;
    int*   partial= (int*)p;   p += (size_t)256 * 4;
    int2*  edata  = (int2*)p;  p += (size_t)N_EDGES * 8;
    float* Wcat   = (float*)p; p += (size_t)64 * 128 * 4;
    float* wca    = (float*)p; p += (size_t)64 * 4;

    hipMemsetAsync(degi, 0, (size_t)N_NODES * 4, stream);

    kw_kernel<<<16, 256, 0, stream>>>(W2, We, Wa, Wcat, wca);
    node_kernel<<<1024, 256, 0, stream>>>(h, Wn, Wa, z, asrc, adst);
    hist_kernel<<<(N_EDGES + 255) / 256, 256, 0, stream>>>(dst, degi);
    scan1_kernel<<<NB1, 256, 0, stream>>>(degi, partial);
    scan2_kernel<<<1, 256, 0, stream>>>(partial);
    scan3_kernel<<<NB1, 256, 0, stream>>>(degi, partial, start, cursor);
    scatter_kernel<<<(N_EDGES + 255) / 256, 256, 0, stream>>>(src, dst, cursor, edata);
    agg_kernel<<<N_NODES / 4, 256, 0, stream>>>(edge_feat, edata, start, degi,
                                                asrc, adst, z, wca, Wcat, out);
}

// Round 3
// 355.318 us; speedup vs baseline: 1.4633x; 1.1121x over previous
//
#include <hip/hip_runtime.h>
#include <math.h>

#define N_NODES 50000
#define N_EDGES 800000
#define NB1 196  // ceil(50000/256)

// Derived weights:
//   Wcat[i][m]    = sum_k W2[i][64+k]*We[k][m]   (edge-feat path, m<64)
//   Wcat[i][64+m] = W2[i*96+m]                   (z-src path)
//   wca[m] = sum_k Wa[64+k]*We[k][m]
__global__ void kw_kernel(const float* __restrict__ W2, const float* __restrict__ We,
                          const float* __restrict__ Wa,
                          float* __restrict__ Wcat, float* __restrict__ wca) {
    int t = blockIdx.x * blockDim.x + threadIdx.x;
    if (t < 64 * 64) {
        int i = t >> 6, m = t & 63;
        float acc = 0.f;
        #pragma unroll
        for (int k = 0; k < 32; ++k) acc += W2[i * 96 + 64 + k] * We[k * 64 + m];
        Wcat[i * 128 + m] = acc;
        Wcat[i * 128 + 64 + m] = W2[i * 96 + m];
    }
    if (t < 64) {
        float acc = 0.f;
        #pragma unroll
        for (int k = 0; k < 32; ++k) acc += Wa[64 + k] * We[k * 64 + t];
        wca[t] = acc;
    }
}

// Per-node: z = h@Wn^T, asrc = z.Wa[0:64], adst = z.Wa[96:160]
__global__ __launch_bounds__(256) void node_kernel(
    const float* __restrict__ h, const float* __restrict__ Wn,
    const float* __restrict__ Wa,
    float* __restrict__ z, float* __restrict__ asrc, float* __restrict__ adst)
{
    __shared__ float sWn[64 * 132];   // stride 132: 16B-aligned rows
    __shared__ float sh[4][128];
    int t = threadIdx.x;
    for (int idx = t; idx < 64 * 128; idx += 256) {
        int r = idx >> 7, c = idx & 127;
        sWn[r * 132 + c] = Wn[idx];
    }
    int w = t >> 6, l = t & 63;
    float wa0 = Wa[l], wa2 = Wa[96 + l];
    __syncthreads();
    for (int n0 = blockIdx.x * 4; n0 < N_NODES; n0 += gridDim.x * 4) {
        if (t < 128) {
            int nn = t >> 5, c4 = t & 31;
            int n = n0 + nn;
            if (n < N_NODES)
                ((float4*)&sh[nn][0])[c4] = ((const float4*)h)[(size_t)n * 32 + c4];
        }
        __syncthreads();
        int n = n0 + w;
        if (n < N_NODES) {
            float acc = 0.f;
            #pragma unroll
            for (int q = 0; q < 32; ++q) {
                float4 wv = *(const float4*)&sWn[l * 132 + q * 4];
                float4 hv = *(const float4*)&sh[w][q * 4];
                acc += wv.x * hv.x + wv.y * hv.y + wv.z * hv.z + wv.w * hv.w;
            }
            z[(size_t)n * 64 + l] = acc;
            float p0 = acc * wa0, p1 = acc * wa2;
            #pragma unroll
            for (int off = 32; off; off >>= 1) {
                p0 += __shfl_xor(p0, off);
                p1 += __shfl_xor(p1, off);
            }
            if (l == 0) { asrc[n] = p0; adst[n] = p1; }
        }
        __syncthreads();
    }
}

// ---- CSR build ----
__global__ void hist_kernel(const int* __restrict__ dst, int* __restrict__ degi) {
    int e = blockIdx.x * 256 + threadIdx.x;
    if (e < N_EDGES) atomicAdd(&degi[dst[e]], 1);
}

__global__ __launch_bounds__(256) void scan1_kernel(const int* __restrict__ degi,
                                                    int* __restrict__ partial) {
    int t = threadIdx.x, i = blockIdx.x * 256 + t;
    int d = (i < N_NODES) ? degi[i] : 0;
    #pragma unroll
    for (int off = 32; off; off >>= 1) d += __shfl_down(d, off);
    __shared__ int wsum[4];
    if ((t & 63) == 0) wsum[t >> 6] = d;
    __syncthreads();
    if (t == 0) partial[blockIdx.x] = wsum[0] + wsum[1] + wsum[2] + wsum[3];
}

__global__ __launch_bounds__(256) void scan2_kernel(int* __restrict__ partial) {
    __shared__ int s[256];
    int t = threadIdx.x;
    int v = (t < NB1) ? partial[t] : 0;
    s[t] = v; __syncthreads();
    for (int off = 1; off < 256; off <<= 1) {
        int x = (t >= off) ? s[t - off] : 0;
        __syncthreads();
        s[t] += x;
        __syncthreads();
    }
    if (t < NB1) partial[t] = s[t] - v;   // exclusive, in place
}

__global__ __launch_bounds__(256) void scan3_kernel(const int* __restrict__ degi,
                                                    const int* __restrict__ partial,
                                                    int* __restrict__ start,
                                                    int* __restrict__ cursor) {
    __shared__ int s[256];
    int t = threadIdx.x, i = blockIdx.x * 256 + t;
    int d = (i < N_NODES) ? degi[i] : 0;
    s[t] = d; __syncthreads();
    for (int off = 1; off < 256; off <<= 1) {
        int x = (t >= off) ? s[t - off] : 0;
        __syncthreads();
        s[t] += x;
        __syncthreads();
    }
    if (i < N_NODES) {
        int st = partial[blockIdx.x] + s[t] - d;
        start[i] = st;
        cursor[i] = st;
    }
}

__global__ void scatter_kernel(const int* __restrict__ src, const int* __restrict__ dst,
                               int* __restrict__ cursor, int2* __restrict__ edata) {
    int e = blockIdx.x * 256 + threadIdx.x;
    if (e < N_EDGES) {
        int d = dst[e];
        int pos = atomicAdd(&cursor[d], 1);
        edata[pos] = make_int2(e, src[e]);
    }
}

// ---- aggregation: one wave per node; scalarized metadata, 8-deep load batching ----
__global__ __launch_bounds__(256) void agg_kernel(
    const float* __restrict__ edge_feat, const int2* __restrict__ edata,
    const int* __restrict__ start, const int* __restrict__ degi,
    const float* __restrict__ asrc, const float* __restrict__ adst,
    const float* __restrict__ z, const float* __restrict__ wca,
    const float* __restrict__ Wcat, float* __restrict__ out)
{
    __shared__ float stu[4][132];
    int t = threadIdx.x, w = t >> 6, l = t & 63;
    float wcal = wca[l];
    int d    = __builtin_amdgcn_readfirstlane(blockIdx.x * 4 + w);  // wave-uniform
    int base = __builtin_amdgcn_readfirstlane(start[d]);
    int deg  = __builtin_amdgcn_readfirstlane(degi[d]);
    float ad = adst[d];
    float tm = 0.f, um = 0.f, den = 0.f;

    for (int c = 0; c < deg; c += 8) {
        int cnt = deg - c;  // wave-uniform guard
        float ef0=0.f,ef1=0.f,ef2=0.f,ef3=0.f,ef4=0.f,ef5=0.f,ef6=0.f,ef7=0.f;
        float zl0=0.f,zl1=0.f,zl2=0.f,zl3=0.f,zl4=0.f,zl5=0.f,zl6=0.f,zl7=0.f;
        float ax0=0.f,ax1=0.f,ax2=0.f,ax3=0.f,ax4=0.f,ax5=0.f,ax6=0.f,ax7=0.f;

        // Phase 1: batch all loads (addresses from scalar edata loads)
        #define LOADJ(J, EF, ZL, AX)                                        \
            if (J < cnt) {                                                  \
                int2 es = edata[base + c + J];                              \
                EF = edge_feat[(size_t)es.x * 64 + l];                      \
                ZL = z[(size_t)es.y * 64 + l];                              \
                AX = asrc[es.y];                                            \
            }
        LOADJ(0, ef0, zl0, ax0) LOADJ(1, ef1, zl1, ax1)
        LOADJ(2, ef2, zl2, ax2) LOADJ(3, ef3, zl3, ax3)
        LOADJ(4, ef4, zl4, ax4) LOADJ(5, ef5, zl5, ax5)
        LOADJ(6, ef6, zl6, ax6) LOADJ(7, ef7, zl7, ax7)
        #undef LOADJ

        // Phase 2: independent dot/exp/accumulate chains
        #define COMPJ(J, EF, ZL, AX)                                        \
            if (J < cnt) {                                                  \
                float p = EF * wcal;                                        \
                p += __shfl_xor(p, 32); p += __shfl_xor(p, 16);             \
                p += __shfl_xor(p, 8);  p += __shfl_xor(p, 4);              \
                p += __shfl_xor(p, 2);  p += __shfl_xor(p, 1);              \
                float a = AX + p + ad;                                      \
                float s = a > 0.f ? a : 0.01f * a;                          \
                float ex = __expf(s);                                       \
                tm += ex * EF; um += ex * ZL; den += ex;                    \
            }
        COMPJ(0, ef0, zl0, ax0) COMPJ(1, ef1, zl1, ax1)
        COMPJ(2, ef2, zl2, ax2) COMPJ(3, ef3, zl3, ax3)
        COMPJ(4, ef4, zl4, ax4) COMPJ(5, ef5, zl5, ax5)
        COMPJ(6, ef6, zl6, ax6) COMPJ(7, ef7, zl7, ax7)
        #undef COMPJ
    }

    // per-node epilogue: out = ([t,u] @ Wcat^T) / den
    stu[w][l] = tm;
    stu[w][64 + l] = um;
    if (deg > 0) {
        float acc = 0.f;
        #pragma unroll
        for (int q = 0; q < 32; ++q) {
            float4 wv = *(const float4*)&Wcat[l * 128 + q * 4];
            float4 tv = *(const float4*)&stu[w][q * 4];
            acc += wv.x * tv.x + wv.y * tv.y + wv.z * tv.z + wv.w * tv.w;
        }
        out[(size_t)d * 64 + l] = acc / den;
    } else {
        out[(size_t)d * 64 + l] = z[(size_t)d * 64 + l];
    }
}

extern "C" void kernel_launch(void* const* d_in, const int* in_sizes, int n_in,
                              void* d_out, int out_size, void* d_ws, size_t ws_size,
                              hipStream_t stream) {
    const float* h         = (const float*)d_in[0];
    const float* edge_feat = (const float*)d_in[1];
    const int*   src       = (const int*)d_in[2];
    const int*   dst       = (const int*)d_in[3];
    const float* Wn        = (const float*)d_in[4];
    const float* We        = (const float*)d_in[5];
    const float* Wa        = (const float*)d_in[6];
    const float* W2        = (const float*)d_in[7];
    float* out = (float*)d_out;

    char* p = (char*)d_ws;
    float* z      = (float*)p; p += (size_t)N_NODES * 64 * 4;
    float* asrc   = (float*)p; p += (size_t)N_NODES * 4;
    float* adst   = (float*)p; p += (size_t)N_NODES * 4;
    int*   degi   = (int*)p;   p += (size_t)N_NODES * 4;
    int*   start  = (int*)p;   p += (size_t)N_NODES * 4;
    int*   cursor = (int*)p;   p += (size_t)N_NODES * 4;
    int*   partial= (int*)p;   p += (size_t)256 * 4;
    int2*  edata  = (int2*)p;  p += (size_t)N_EDGES * 8;
    float* Wcat   = (float*)p; p += (size_t)64 * 128 * 4;
    float* wca    = (float*)p; p += (size_t)64 * 4;

    hipMemsetAsync(degi, 0, (size_t)N_NODES * 4, stream);

    kw_kernel<<<16, 256, 0, stream>>>(W2, We, Wa, Wcat, wca);
    node_kernel<<<1024, 256, 0, stream>>>(h, Wn, Wa, z, asrc, adst);
    hist_kernel<<<(N_EDGES + 255) / 256, 256, 0, stream>>>(dst, degi);
    scan1_kernel<<<NB1, 256, 0, stream>>>(degi, partial);
    scan2_kernel<<<1, 256, 0, stream>>>(partial);
    scan3_kernel<<<NB1, 256, 0, stream>>>(degi, partial, start, cursor);
    scatter_kernel<<<(N_EDGES + 255) / 256, 256, 0, stream>>>(src, dst, cursor, edata);
    agg_kernel<<<N_NODES / 4, 256, 0, stream>>>(edge_feat, edata, start, degi,
                                                asrc, adst, z, wca, Wcat, out);
}